// Round 3
// baseline (51486.816 us; speedup 1.0000x reference)
//
#include <hip/hip_runtime.h>
#include <stdint.h>

// LSTM seq2seq (B=64, S=2048, H=512, L=2) as ONE persistent kernel, v3.
// 128 WGs x 256 thr; WG w owns hidden cols [4w,4w+4) -> gate rows {4w+r+512q}.
// v3: H reads are plain L2-cached loads (acquire fence w/ L2 inv once per
// phase by wave0); H layout packed so one A-frag = one dwordx4; barrier flags
// packed + s_sleep backoff; decoder split into symmetric phases with fc done
// as an extra MFMA against an fcW-broadcast B-fragment (no shuffles/atomics).

#define NWG   128
#define NTHR  256
#define SEQ   2048
#define NB    64
#define NH    512

typedef _Float16 half8v __attribute__((ext_vector_type(8)));
typedef float    f32x4  __attribute__((ext_vector_type(4)));

struct P {
  const float *x;
  const float *eWih0, *eWhh0, *ebih0, *ebhh0;
  const float *eWih1, *eWhh1, *ebih1, *ebhh1;
  const float *dWih0, *dWhh0, *dbih0, *dbhh0;
  const float *dWih1, *dWhh1, *dbih1, *dbhh1;
  const float *fcW, *fcb;
  float *out;
  unsigned short *H0, *H1;   // 2 parities x [16 ks][4 lo4][64 b][8 half] (32768 halfs/par)
  unsigned *arrive;          // [2 slot][128 wg] packed 4B
};

__device__ __forceinline__ void stg64(uint64_t* p, uint64_t v) {
  __hip_atomic_store(p, v, __ATOMIC_RELAXED, __HIP_MEMORY_SCOPE_AGENT);
}
__device__ __forceinline__ float sigf(float v)   { return 1.f / (1.f + __expf(-v)); }
__device__ __forceinline__ float tanhf_(float v) { return 2.f * sigf(2.f * v) - 1.f; }

__global__ __launch_bounds__(NTHR, 1) void lstm_persist(P p) {
  __shared__ half8v wlds[3][16][64];   // 48KB: slot0=Whh0, slot1=Wih1, slot2=Whh1
  __shared__ half8v fcw_c[16][4];      // 1KB: fcW broadcast B-frag (per ks,lo4)
  __shared__ float  bias_lds[4][16];   // e0,e1,d0,d1 (bih+bhh)
  __shared__ float  w0v_lds[2][16];    // Wih0 col (enc,dec)
  __shared__ float  c_lds[2][NB][4];   // fp32 cell state
  __shared__ float  h_tmp[2][NB][4];   // fp32 h' staging
  __shared__ float  fcb_s;

  const int wg   = blockIdx.x;
  const int tid  = threadIdx.x;
  const int lane = tid & 63;
  const int wv   = tid >> 6;
  const int Mb   = wv * 16;
  const int lo4  = lane >> 4;
  const int nn   = lane & 15;
  const int q    = nn >> 2, r = nn & 3;
  const int wksl = (wg >> 3) * 4 + (wg & 3);   // writer group index
  const int whi  = (wg >> 2) & 1;              // writer 8B half within 16B group

  unsigned epoch = 0;

  // ---------------- grid barrier: packed flags, sleep backoff, L2-inv acquire ----
  auto gbar = [&]() {
    epoch++;
    __syncthreads();                           // all waves' stores drained (vmcnt0)
    if (tid == 0)
      __hip_atomic_store(p.arrive + (epoch & 1u) * NWG + wg, epoch,
                         __ATOMIC_RELEASE, __HIP_MEMORY_SCOPE_AGENT);
    if (tid < 64) {
      const uint64_t tgt = (uint64_t)epoch * 0x100000001ull;
      const uint64_t* f = (const uint64_t*)(p.arrive + (epoch & 1u) * NWG) + tid;
      while (__hip_atomic_load(f, __ATOMIC_RELAXED, __HIP_MEMORY_SCOPE_AGENT) != tgt)
        __builtin_amdgcn_s_sleep(2);
      __builtin_amdgcn_fence(__ATOMIC_ACQUIRE, "agent");      // L1+L2 inv (wave 0)
    } else {
      __builtin_amdgcn_fence(__ATOMIC_ACQUIRE, "workgroup");  // ordering only
    }
    __syncthreads();                           // inv complete before any plain load
  };

  // ---------------- weight gather: global fp32 -> LDS fp16 B-frags ----------------
  auto loadW = [&](int slot, const float *__restrict__ W) {
    for (int idx = tid; idx < 16 * 64; idx += NTHR) {
      const int ks = idx >> 6, l = idx & 63;
      const int g = 4 * wg + (l & 3) + 512 * ((l >> 2) & 3);
      const float *base = W + (size_t)g * NH + 32 * ks + 4 * (l >> 4);
      f32x4 wa, wb;
      __builtin_memcpy(&wa, base, 16);
      __builtin_memcpy(&wb, base + 16, 16);
      half8v h;
      h[0] = (_Float16)wa[0]; h[1] = (_Float16)wa[1];
      h[2] = (_Float16)wa[2]; h[3] = (_Float16)wa[3];
      h[4] = (_Float16)wb[0]; h[5] = (_Float16)wb[1];
      h[6] = (_Float16)wb[2]; h[7] = (_Float16)wb[3];
      wlds[slot][ks][l] = h;
    }
  };

  // ---------------- A-fragment load: 16 x dwordx4, plain cached ----------------
  auto ldA = [&](const unsigned short* Hb, half8v* A) {
#pragma unroll
    for (int ks = 0; ks < 16; ++ks)
      A[ks] = *(const half8v*)(Hb + ((size_t)(ks * 4 + lo4) * 64 + (Mb + nn)) * 8);
  };

  // ---------------- gates -> (c,h'); h' fp32 into h_tmp[sel] ----------------
  auto cell = [&](const f32x4 &acc, const float* bias16, const float* w016,
                  const float* xv4, int sel, float* cl) {
    float v[4];
#pragma unroll
    for (int j = 0; j < 4; ++j) {
      const float g = acc[j] + bias16[nn] + xv4[j] * w016[nn];
      v[j] = (q == 2) ? tanhf_(g) : sigf(g);
    }
    float s4[4], s8[4], s12[4];
#pragma unroll
    for (int j = 0; j < 4; ++j) {
      s4[j]  = __shfl_xor(v[j], 4, 64);
      s8[j]  = __shfl_xor(v[j], 8, 64);
      s12[j] = __shfl_xor(v[j], 12, 64);
    }
    if (q == 0) {
#pragma unroll
      for (int j = 0; j < 4; ++j) {
        const int b = Mb + 4 * lo4 + j;
        const float co = cl[b * 4 + r];
        const float cn = s4[j] * co + v[j] * s8[j];
        cl[b * 4 + r] = cn;
        h_tmp[sel][b][r] = s12[j] * tanhf_(cn);
      }
    }
  };

  auto packrow = [&](int sel, int b) -> uint64_t {
    union { uint64_t u; _Float16 h[4]; } cv;
#pragma unroll
    for (int k = 0; k < 4; ++k) cv.h[k] = (_Float16)h_tmp[sel][b][k];
    return cv.u;
  };
  auto publish = [&](unsigned short* Hpar, int sel, int b) {
    stg64((uint64_t*)Hpar + ((size_t)wksl * 64 + b) * 2 + whi, packrow(sel, b));
  };

  // ================= init =================
  loadW(0, p.eWhh0); loadW(1, p.eWih1); loadW(2, p.eWhh1);
  if (tid < 16) {
    const int g = 4 * wg + (tid & 3) + 512 * (tid >> 2);
    bias_lds[0][tid] = p.ebih0[g] + p.ebhh0[g];
    bias_lds[1][tid] = p.ebih1[g] + p.ebhh1[g];
    bias_lds[2][tid] = p.dbih0[g] + p.dbhh0[g];
    bias_lds[3][tid] = p.dbih1[g] + p.dbhh1[g];
    w0v_lds[0][tid] = p.eWih0[g];
    w0v_lds[1][tid] = p.dWih0[g];
  }
  if (tid < 64) {                       // fcW broadcast B-frag
    const int ks = tid >> 2, l4 = tid & 3;
    half8v h;
#pragma unroll
    for (int j = 0; j < 4; ++j) {
      h[j]     = (_Float16)p.fcW[32 * ks + 4 * l4 + j];
      h[4 + j] = (_Float16)p.fcW[32 * ks + 4 * l4 + 16 + j];
    }
    fcw_c[ks][l4] = h;
  }
  if (tid == 0) fcb_s = p.fcb[0];
  for (int i = tid; i < 2 * NB * 4; i += NTHR) (&c_lds[0][0][0])[i] = 0.f;
  if (tid < 64) {                       // h0(-1)=0 in H0[1]; h1(-1)=0 in H1[0]
    stg64((uint64_t*)(p.H0 + 32768) + ((size_t)wksl * 64 + tid) * 2 + whi, 0ull);
    stg64((uint64_t*)p.H1 + ((size_t)wksl * 64 + tid) * 2 + whi, 0ull);
  }
  float xv[4];
#pragma unroll
  for (int j = 0; j < 4; ++j) xv[j] = p.x[(size_t)(Mb + 4 * lo4 + j) * SEQ];
  const float zv4[4] = {0.f, 0.f, 0.f, 0.f};
  gbar();

  // ================= encoder: L0(t) || L1(t-1), 1 barrier/phase =================
  for (int t = 0; t <= SEQ; ++t) {
    const int ri = (t + 1) & 1, wi = t & 1;
    const bool d0 = (t < SEQ), d1 = (t > 0);
    half8v A0[16], A1[16];
    ldA(p.H0 + ri * 32768, A0);
    if (d1) ldA(p.H1 + ri * 32768, A1);
    f32x4 aL0 = {0.f, 0.f, 0.f, 0.f}, aL1 = {0.f, 0.f, 0.f, 0.f};
#pragma unroll
    for (int ks = 0; ks < 16; ++ks) {
      if (d0) aL0 = __builtin_amdgcn_mfma_f32_16x16x32_f16(A0[ks], wlds[0][ks][lane], aL0, 0, 0, 0);
      if (d1) aL1 = __builtin_amdgcn_mfma_f32_16x16x32_f16(A0[ks], wlds[1][ks][lane], aL1, 0, 0, 0);
    }
    if (d1) {
#pragma unroll
      for (int ks = 0; ks < 16; ++ks)
        aL1 = __builtin_amdgcn_mfma_f32_16x16x32_f16(A1[ks], wlds[2][ks][lane], aL1, 0, 0, 0);
    }
    if (d0) cell(aL0, bias_lds[0], w0v_lds[0], xv, 0, &c_lds[0][0][0]);
    if (d1) cell(aL1, bias_lds[1], w0v_lds[0], zv4, 1, &c_lds[1][0][0]);
    if (t + 1 < SEQ) {
#pragma unroll
      for (int j = 0; j < 4; ++j) xv[j] = p.x[(size_t)(Mb + 4 * lo4 + j) * SEQ + (t + 1)];
    }
    __syncthreads();
    if (tid < 64) {
      if (d0) publish(p.H0 + wi * 32768, 0, tid);
      if (d1) publish(p.H1 + wi * 32768, 1, tid);
    }
    gbar();
  }
  // encoder leaves: h0_enc in H0[1], h1_enc in H1[0]

  // ================= enc -> dec transition (no extra barrier) =================
  loadW(0, p.dWhh0); loadW(1, p.dWih1); loadW(2, p.dWhh1);
  __syncthreads();
  f32x4 accPre0 = {0.f, 0.f, 0.f, 0.f};
  {
    half8v A0[16];
    ldA(p.H0 + 32768, A0);                       // h0_enc
#pragma unroll
    for (int ks = 0; ks < 16; ++ks)
      accPre0 = __builtin_amdgcn_mfma_f32_16x16x32_f16(A0[ks], wlds[0][ks][lane], accPre0, 0, 0, 0);
  }

  // ================= decoder: A(t)=fc+Whh1+cell0, B(t)=Wih1+Whh0+cell1 ==========
  f32x4 accPre1;
  for (int t = 0; t < SEQ; ++t) {
    // ---- A(t): read H1[t&1] = h1(t-1) ----
    {
      half8v A1[16];
      ldA(p.H1 + (t & 1) * 32768, A1);
      f32x4 aP1 = {0.f, 0.f, 0.f, 0.f}, afc = {0.f, 0.f, 0.f, 0.f};
#pragma unroll
      for (int ks = 0; ks < 16; ++ks) {
        aP1 = __builtin_amdgcn_mfma_f32_16x16x32_f16(A1[ks], wlds[2][ks][lane], aP1, 0, 0, 0);
        afc = __builtin_amdgcn_mfma_f32_16x16x32_f16(A1[ks], fcw_c[ks][lo4],    afc, 0, 0, 0);
      }
      accPre1 = aP1;
      float yv4[4];
#pragma unroll
      for (int j = 0; j < 4; ++j) yv4[j] = (t == 0) ? 0.f : (afc[j] + fcb_s);
      if (t > 0 && wg == 0 && nn == 0) {
#pragma unroll
        for (int j = 0; j < 4; ++j)
          p.out[(size_t)(Mb + 4 * lo4 + j) * SEQ + (t - 1)] = yv4[j];
      }
      cell(accPre0, bias_lds[2], w0v_lds[1], yv4, 0, &c_lds[0][0][0]);
      __syncthreads();
      if (tid < 64) publish(p.H0 + (t & 1) * 32768, 0, tid);
      gbar();
    }
    // ---- B(t): read H0[t&1] = h0(t) ----
    {
      half8v A0[16];
      ldA(p.H0 + (t & 1) * 32768, A0);
      f32x4 a0n = {0.f, 0.f, 0.f, 0.f};
#pragma unroll
      for (int ks = 0; ks < 16; ++ks) {
        accPre1 = __builtin_amdgcn_mfma_f32_16x16x32_f16(A0[ks], wlds[1][ks][lane], accPre1, 0, 0, 0);
        a0n     = __builtin_amdgcn_mfma_f32_16x16x32_f16(A0[ks], wlds[0][ks][lane], a0n,     0, 0, 0);
      }
      cell(accPre1, bias_lds[3], w0v_lds[1], zv4, 1, &c_lds[1][0][0]);
      accPre0 = a0n;
      __syncthreads();
      if (tid < 64) publish(p.H1 + ((t + 1) & 1) * 32768, 1, tid);
      gbar();
    }
  }

  // ================= epilogue: y(2047) = fc(h1(2047)), in H1[0] =================
  if (wg == 0) {
    half8v A1[16];
    ldA(p.H1, A1);
    f32x4 afc = {0.f, 0.f, 0.f, 0.f};
#pragma unroll
    for (int ks = 0; ks < 16; ++ks)
      afc = __builtin_amdgcn_mfma_f32_16x16x32_f16(A1[ks], fcw_c[ks][lo4], afc, 0, 0, 0);
    if (nn == 0) {
#pragma unroll
      for (int j = 0; j < 4; ++j)
        p.out[(size_t)(Mb + 4 * lo4 + j) * SEQ + (SEQ - 1)] = afc[j] + fcb_s;
    }
  }
}

extern "C" void kernel_launch(void* const* d_in, const int* in_sizes, int n_in,
                              void* d_out, int out_size, void* d_ws, size_t ws_size,
                              hipStream_t stream) {
  (void)in_sizes; (void)n_in; (void)out_size; (void)ws_size;
  P p;
  p.x     = (const float*)d_in[0];
  p.eWih0 = (const float*)d_in[1];  p.eWhh0 = (const float*)d_in[2];
  p.ebih0 = (const float*)d_in[3];  p.ebhh0 = (const float*)d_in[4];
  p.eWih1 = (const float*)d_in[5];  p.eWhh1 = (const float*)d_in[6];
  p.ebih1 = (const float*)d_in[7];  p.ebhh1 = (const float*)d_in[8];
  p.dWih0 = (const float*)d_in[9];  p.dWhh0 = (const float*)d_in[10];
  p.dbih0 = (const float*)d_in[11]; p.dbhh0 = (const float*)d_in[12];
  p.dWih1 = (const float*)d_in[13]; p.dWhh1 = (const float*)d_in[14];
  p.dbih1 = (const float*)d_in[15]; p.dbhh1 = (const float*)d_in[16];
  p.fcW   = (const float*)d_in[17]; p.fcb   = (const float*)d_in[18];
  p.out   = (float*)d_out;

  p.H0     = (unsigned short*)d_ws;                // 128 KB (2 parities x 64 KB)
  p.H1     = (unsigned short*)d_ws + 2 * 32768;    // 128 KB
  p.arrive = (unsigned*)((char*)d_ws + 262144);    // 1 KB packed flags

  lstm_persist<<<dim3(NWG), dim3(NTHR), 0, stream>>>(p);
}

// Round 6
// 32172.269 us; speedup vs baseline: 1.6003x; 1.6003x over previous
//
#include <hip/hip_runtime.h>
#include <stdint.h>

// LSTM seq2seq (B=64, S=2048, H=512, L=2) as ONE persistent kernel, v6.
// = v2's PROVEN transport (compiler-emitted agent-scope atomics only; no
//   hand-rolled cache bits - v4/v5 post-mortem) 
// + v3's PROVEN math/layout (packed 16B A-frags, fc-as-broadcast-MFMA,
//   decoder A/B phases each reading one H matrix, Whh0.h0 hoisted)
// + NEW cheap barrier: 8 padded monotone counters, fetch_add arrive, 8-lane
//   poll (cnt[i] >= 16*epoch); zeroed each launch via hipMemsetAsync.
// 128 WGs x 256 thr; WG owns 4 hidden cols -> 16 gate rows {4wg+r+512q}.

#define NWG   128
#define NTHR  256
#define SEQ   2048
#define NB    64
#define NH    512

typedef _Float16 half8v __attribute__((ext_vector_type(8)));
typedef float    f32x4  __attribute__((ext_vector_type(4)));

struct P {
  const float *x;
  const float *eWih0, *eWhh0, *ebih0, *ebhh0;
  const float *eWih1, *eWhh1, *ebih1, *ebhh1;
  const float *dWih0, *dWhh0, *dbih0, *dbhh0;
  const float *dWih1, *dWhh1, *dbih1, *dbhh1;
  const float *fcW, *fcb;
  float *out;
  unsigned short *H0, *H1;   // 2 parities x [ks4=0..63][m=0..63][8 half] = 64KB each
  unsigned *cnt;             // 8 counters, 128B apart (zeroed every launch)
};

__device__ __forceinline__ uint64_t ldg64(const uint64_t* p) {
  return __hip_atomic_load(p, __ATOMIC_RELAXED, __HIP_MEMORY_SCOPE_AGENT);
}
__device__ __forceinline__ void stg64(uint64_t* p, uint64_t v) {
  __hip_atomic_store(p, v, __ATOMIC_RELAXED, __HIP_MEMORY_SCOPE_AGENT);
}
__device__ __forceinline__ float sigf(float v)   { return 1.f / (1.f + __expf(-v)); }
__device__ __forceinline__ float tanhf_(float v) { return 2.f * sigf(2.f * v) - 1.f; }

__global__ __launch_bounds__(NTHR, 1) void lstm_persist(P p) {
  __shared__ half8v wlds[3][16][64];   // 48KB: slot0=Whh0, slot1=Wih1, slot2=Whh1
  __shared__ half8v fcw_c[16][4];      // fcW broadcast B-frags (same sigma)
  __shared__ float  bias_lds[4][16];   // e0,e1,d0,d1 (bih+bhh)
  __shared__ float  w0v_lds[2][16];    // Wih0 col (enc,dec)
  __shared__ float  c_lds[2][NB][4];   // fp32 cell state
  __shared__ float  h_tmp[2][NB][4];   // fp32 h' staging
  __shared__ float  fcb_s;

  const int wg   = blockIdx.x;
  const int tid  = threadIdx.x;
  const int lane = tid & 63;
  const int wv   = tid >> 6;
  const int Mb   = wv * 16;
  const int lo4  = lane >> 4;
  const int nn   = lane & 15;
  const int q    = nn >> 2, r = nn & 3;
  const int wksl = (wg >> 3) * 4 + (wg & 3);   // writer ks4 slot
  const int whi  = (wg >> 2) & 1;              // writer 8B half (e<4 / e>=4)

  unsigned epoch = 0;

  // ---------------- grid barrier: 8 monotone counters ----------------
  auto gbar = [&]() {
    epoch++;
    __syncthreads();                           // all waves' stores drained
    if (tid == 0)
      __hip_atomic_fetch_add(p.cnt + (wg & 7) * 32, 1u,
                             __ATOMIC_RELEASE, __HIP_MEMORY_SCOPE_AGENT);
    if (tid < 8) {
      const unsigned tgt = 16u * epoch;
      while (__hip_atomic_load(p.cnt + tid * 32,
                               __ATOMIC_RELAXED, __HIP_MEMORY_SCOPE_AGENT) < tgt) {}
    }
    __builtin_amdgcn_fence(__ATOMIC_ACQUIRE, "workgroup");
    __syncthreads();
  };

  // -------- weight gather: global fp32 -> LDS fp16 B-frags (sigma) --------
  auto loadW = [&](int slot, const float *__restrict__ W) {
    for (int idx = tid; idx < 16 * 64; idx += NTHR) {
      const int ks = idx >> 6, l = idx & 63;
      const int g = 4 * wg + (l & 3) + 512 * ((l >> 2) & 3);
      const float *base = W + (size_t)g * NH + 32 * ks + 4 * (l >> 4);
      f32x4 wa, wb;
      __builtin_memcpy(&wa, base, 16);
      __builtin_memcpy(&wb, base + 16, 16);
      half8v h;
      h[0] = (_Float16)wa[0]; h[1] = (_Float16)wa[1];
      h[2] = (_Float16)wa[2]; h[3] = (_Float16)wa[3];
      h[4] = (_Float16)wb[0]; h[5] = (_Float16)wb[1];
      h[6] = (_Float16)wb[2]; h[7] = (_Float16)wb[3];
      wlds[slot][ks][l] = h;
    }
  };

  // -------- A-fragment load: 32 x 8B agent-atomic, staged then packed --------
  auto ldA = [&](const unsigned short* Hb, half8v* A) {
    const uint64_t* bp = (const uint64_t*)Hb + (size_t)(Mb + nn) * 2 + lo4 * 128;
    uint64_t u0[16], u1[16];
#pragma unroll
    for (int ks = 0; ks < 16; ++ks) {
      u0[ks] = ldg64(bp + ks * 512);
      u1[ks] = ldg64(bp + ks * 512 + 1);
    }
#pragma unroll
    for (int ks = 0; ks < 16; ++ks) {
      union { uint64_t u[2]; half8v h; } T;
      T.u[0] = u0[ks]; T.u[1] = u1[ks];
      A[ks] = T.h;
    }
  };

  // -------- gates -> (c,h'); h' fp32 into h_tmp[sel] --------
  auto cell = [&](const f32x4 &acc, const float* bias16, const float* w016,
                  const float* xv4, int sel, float* cl) {
    float v[4];
#pragma unroll
    for (int j = 0; j < 4; ++j) {
      const float g = acc[j] + bias16[nn] + xv4[j] * w016[nn];
      v[j] = (q == 2) ? tanhf_(g) : sigf(g);
    }
    float s4[4], s8[4], s12[4];
#pragma unroll
    for (int j = 0; j < 4; ++j) {
      s4[j]  = __shfl_xor(v[j], 4, 64);
      s8[j]  = __shfl_xor(v[j], 8, 64);
      s12[j] = __shfl_xor(v[j], 12, 64);
    }
    if (q == 0) {
#pragma unroll
      for (int j = 0; j < 4; ++j) {
        const int b = Mb + 4 * lo4 + j;
        const float co = cl[b * 4 + r];
        const float cn = s4[j] * co + v[j] * s8[j];
        cl[b * 4 + r] = cn;
        h_tmp[sel][b][r] = s12[j] * tanhf_(cn);
      }
    }
  };

  auto packrow = [&](int sel, int b) -> uint64_t {
    union { uint64_t u; _Float16 h[4]; } cv;
#pragma unroll
    for (int k = 0; k < 4; ++k) cv.h[k] = (_Float16)h_tmp[sel][b][k];
    return cv.u;
  };
  auto publish = [&](unsigned short* Hpar, int sel, int b) {
    stg64((uint64_t*)Hpar + ((size_t)wksl * 64 + b) * 2 + whi, packrow(sel, b));
  };

  // ================= init =================
  loadW(0, p.eWhh0); loadW(1, p.eWih1); loadW(2, p.eWhh1);
  if (tid < 16) {
    const int g = 4 * wg + (tid & 3) + 512 * (tid >> 2);
    bias_lds[0][tid] = p.ebih0[g] + p.ebhh0[g];
    bias_lds[1][tid] = p.ebih1[g] + p.ebhh1[g];
    bias_lds[2][tid] = p.dbih0[g] + p.dbhh0[g];
    bias_lds[3][tid] = p.dbih1[g] + p.dbhh1[g];
    w0v_lds[0][tid] = p.eWih0[g];
    w0v_lds[1][tid] = p.dWih0[g];
  }
  if (tid < 64) {                       // fcW broadcast B-frag (sigma)
    const int ks = tid >> 2, l4 = tid & 3;
    half8v h;
#pragma unroll
    for (int j = 0; j < 4; ++j) {
      h[j]     = (_Float16)p.fcW[32 * ks + 4 * l4 + j];
      h[4 + j] = (_Float16)p.fcW[32 * ks + 4 * l4 + 16 + j];
    }
    fcw_c[ks][l4] = h;
  }
  if (tid == 0) fcb_s = p.fcb[0];
  for (int i = tid; i < 2 * NB * 4; i += NTHR) (&c_lds[0][0][0])[i] = 0.f;
  if (tid < 64) {                       // h0(-1)=0 in H0[1]; h1(-1)=0 in H1[0]
    stg64((uint64_t*)(p.H0 + 32768) + ((size_t)wksl * 64 + tid) * 2 + whi, 0ull);
    stg64((uint64_t*)p.H1 + ((size_t)wksl * 64 + tid) * 2 + whi, 0ull);
  }
  float xv[4];
#pragma unroll
  for (int j = 0; j < 4; ++j) xv[j] = p.x[(size_t)(Mb + 4 * lo4 + j) * SEQ];
  const float zv4[4] = {0.f, 0.f, 0.f, 0.f};
  gbar();

  // ================= encoder: L0(t) || L1(t-1), 1 barrier/phase =================
  for (int t = 0; t <= SEQ; ++t) {
    const int ri = (t + 1) & 1, wi = t & 1;
    const bool d0 = (t < SEQ), d1 = (t > 0);
    half8v A[16];
    f32x4 aL0 = {0.f, 0.f, 0.f, 0.f}, aL1 = {0.f, 0.f, 0.f, 0.f};
    ldA(p.H0 + ri * 32768, A);                   // h0(t-1)
#pragma unroll
    for (int ks = 0; ks < 16; ++ks) {
      if (d0) aL0 = __builtin_amdgcn_mfma_f32_16x16x32_f16(A[ks], wlds[0][ks][lane], aL0, 0, 0, 0);
      if (d1) aL1 = __builtin_amdgcn_mfma_f32_16x16x32_f16(A[ks], wlds[1][ks][lane], aL1, 0, 0, 0);
    }
    if (d1) {
      ldA(p.H1 + ri * 32768, A);                 // h1(t-2)
#pragma unroll
      for (int ks = 0; ks < 16; ++ks)
        aL1 = __builtin_amdgcn_mfma_f32_16x16x32_f16(A[ks], wlds[2][ks][lane], aL1, 0, 0, 0);
    }
    if (d0) cell(aL0, bias_lds[0], w0v_lds[0], xv, 0, &c_lds[0][0][0]);
    if (d1) cell(aL1, bias_lds[1], w0v_lds[0], zv4, 1, &c_lds[1][0][0]);
    if (t + 1 < SEQ) {
#pragma unroll
      for (int j = 0; j < 4; ++j) xv[j] = p.x[(size_t)(Mb + 4 * lo4 + j) * SEQ + (t + 1)];
    }
    __syncthreads();
    if (tid < 64) {
      if (d0) publish(p.H0 + wi * 32768, 0, tid);
      if (d1) publish(p.H1 + wi * 32768, 1, tid);
    }
    gbar();
  }
  // encoder leaves: h0_enc in H0[1], h1_enc in H1[0]

  // ================= enc -> dec transition =================
  loadW(0, p.dWhh0); loadW(1, p.dWih1); loadW(2, p.dWhh1);
  __syncthreads();
  f32x4 accPre0 = {0.f, 0.f, 0.f, 0.f};
  {
    half8v A[16];
    ldA(p.H0 + 32768, A);                        // h0_enc
#pragma unroll
    for (int ks = 0; ks < 16; ++ks)
      accPre0 = __builtin_amdgcn_mfma_f32_16x16x32_f16(A[ks], wlds[0][ks][lane], accPre0, 0, 0, 0);
  }

  // ============ decoder: A(t)=fc+Whh1+cell0, B(t)=Wih1+Whh0+cell1 ============
  f32x4 acc1c = {0.f, 0.f, 0.f, 0.f};
  for (int t = 0; t < SEQ; ++t) {
    { // ---- A(t): reads h1(t-1) in H1[t&1] ----
      half8v A[16];
      ldA(p.H1 + (t & 1) * 32768, A);
      f32x4 aP1 = {0.f, 0.f, 0.f, 0.f}, afc = {0.f, 0.f, 0.f, 0.f};
#pragma unroll
      for (int ks = 0; ks < 16; ++ks) {
        aP1 = __builtin_amdgcn_mfma_f32_16x16x32_f16(A[ks], wlds[2][ks][lane], aP1, 0, 0, 0);
        afc = __builtin_amdgcn_mfma_f32_16x16x32_f16(A[ks], fcw_c[ks][lo4],    afc, 0, 0, 0);
      }
      acc1c = aP1;
      float yv4[4];
#pragma unroll
      for (int j = 0; j < 4; ++j) yv4[j] = (t == 0) ? 0.f : (afc[j] + fcb_s);
      if (t > 0 && wg == 0 && nn == 0) {
#pragma unroll
        for (int j = 0; j < 4; ++j)
          p.out[(size_t)(Mb + 4 * lo4 + j) * SEQ + (t - 1)] = yv4[j];
      }
      cell(accPre0, bias_lds[2], w0v_lds[1], yv4, 0, &c_lds[0][0][0]);
      __syncthreads();
      if (tid < 64) publish(p.H0 + (t & 1) * 32768, 0, tid);
      gbar();
    }
    { // ---- B(t): reads h0(t) in H0[t&1] ----
      half8v A[16];
      ldA(p.H0 + (t & 1) * 32768, A);
      f32x4 a0n = {0.f, 0.f, 0.f, 0.f};
#pragma unroll
      for (int ks = 0; ks < 16; ++ks) {
        acc1c = __builtin_amdgcn_mfma_f32_16x16x32_f16(A[ks], wlds[1][ks][lane], acc1c, 0, 0, 0);
        a0n   = __builtin_amdgcn_mfma_f32_16x16x32_f16(A[ks], wlds[0][ks][lane], a0n,   0, 0, 0);
      }
      cell(acc1c, bias_lds[3], w0v_lds[1], zv4, 1, &c_lds[1][0][0]);
      accPre0 = a0n;
      __syncthreads();
      if (tid < 64) publish(p.H1 + ((t + 1) & 1) * 32768, 1, tid);
      gbar();
    }
  }

  // ================= epilogue: y(2047) = fc(h1(2047)) in H1[0] =================
  if (wg == 0) {
    half8v A[16];
    ldA(p.H1, A);
    f32x4 afc = {0.f, 0.f, 0.f, 0.f};
#pragma unroll
    for (int ks = 0; ks < 16; ++ks)
      afc = __builtin_amdgcn_mfma_f32_16x16x32_f16(A[ks], fcw_c[ks][lo4], afc, 0, 0, 0);
    if (nn == 0) {
#pragma unroll
      for (int j = 0; j < 4; ++j)
        p.out[(size_t)(Mb + 4 * lo4 + j) * SEQ + (SEQ - 1)] = afc[j] + fcb_s;
    }
  }
}

extern "C" void kernel_launch(void* const* d_in, const int* in_sizes, int n_in,
                              void* d_out, int out_size, void* d_ws, size_t ws_size,
                              hipStream_t stream) {
  (void)in_sizes; (void)n_in; (void)out_size; (void)ws_size;
  P p;
  p.x     = (const float*)d_in[0];
  p.eWih0 = (const float*)d_in[1];  p.eWhh0 = (const float*)d_in[2];
  p.ebih0 = (const float*)d_in[3];  p.ebhh0 = (const float*)d_in[4];
  p.eWih1 = (const float*)d_in[5];  p.eWhh1 = (const float*)d_in[6];
  p.ebih1 = (const float*)d_in[7];  p.ebhh1 = (const float*)d_in[8];
  p.dWih0 = (const float*)d_in[9];  p.dWhh0 = (const float*)d_in[10];
  p.dbih0 = (const float*)d_in[11]; p.dbhh0 = (const float*)d_in[12];
  p.dWih1 = (const float*)d_in[13]; p.dWhh1 = (const float*)d_in[14];
  p.dbih1 = (const float*)d_in[15]; p.dbhh1 = (const float*)d_in[16];
  p.fcW   = (const float*)d_in[17]; p.fcb   = (const float*)d_in[18];
  p.out   = (float*)d_out;

  p.H0  = (unsigned short*)d_ws;                 // 128 KB (2 parities x 64 KB)
  p.H1  = (unsigned short*)d_ws + 2 * 32768;     // 128 KB
  p.cnt = (unsigned*)((char*)d_ws + 262144);     // 8 x 128B counters

  // Zero the barrier counters every call (graph-capturable, replay-safe).
  hipMemsetAsync((char*)d_ws + 262144, 0, 1024, stream);

  lstm_persist<<<dim3(NWG), dim3(NTHR), 0, stream>>>(p);
}

// Round 7
// 29289.331 us; speedup vs baseline: 1.7579x; 1.0984x over previous
//
#include <hip/hip_runtime.h>
#include <stdint.h>

// LSTM seq2seq (B=64, S=2048, H=512, L=2) as ONE persistent kernel, v7.
// = v6 (passed, 32.2ms) with the barrier cost attacked:
//   * fetch_add RELAXED (was RELEASE): no per-phase conservative L2 writeback.
//     Safe because all cross-WG data moves via agent-scope relaxed atomics
//     (LLC write-through) and __syncthreads drains vmcnt(0) before s_barrier.
//   * poll backoff s_sleep(2) + 16 counters (was 8, no sleep): kills the LLC
//     poll storm that queued the last-arriver's increment (and throttled clocks).
//   * encoder: both A-frag load blocks issued before either MFMA chain (one
//     exposed LLC round trip instead of two).
// 128 WGs x 256 thr; WG owns 4 hidden cols -> 16 gate rows {4wg+r+512q}.

#define NWG   128
#define NTHR  256
#define SEQ   2048
#define NB    64
#define NH    512

typedef _Float16 half8v __attribute__((ext_vector_type(8)));
typedef float    f32x4  __attribute__((ext_vector_type(4)));

struct P {
  const float *x;
  const float *eWih0, *eWhh0, *ebih0, *ebhh0;
  const float *eWih1, *eWhh1, *ebih1, *ebhh1;
  const float *dWih0, *dWhh0, *dbih0, *dbhh0;
  const float *dWih1, *dWhh1, *dbih1, *dbhh1;
  const float *fcW, *fcb;
  float *out;
  unsigned short *H0, *H1;   // 2 parities x [ks4=0..63][m=0..63][8 half] = 64KB each
  unsigned *cnt;             // 16 counters, 128B apart (zeroed every launch)
};

__device__ __forceinline__ uint64_t ldg64(const uint64_t* p) {
  return __hip_atomic_load(p, __ATOMIC_RELAXED, __HIP_MEMORY_SCOPE_AGENT);
}
__device__ __forceinline__ void stg64(uint64_t* p, uint64_t v) {
  __hip_atomic_store(p, v, __ATOMIC_RELAXED, __HIP_MEMORY_SCOPE_AGENT);
}
__device__ __forceinline__ float sigf(float v)   { return 1.f / (1.f + __expf(-v)); }
__device__ __forceinline__ float tanhf_(float v) { return 2.f * sigf(2.f * v) - 1.f; }

__global__ __launch_bounds__(NTHR, 1) void lstm_persist(P p) {
  __shared__ half8v wlds[3][16][64];   // 48KB: slot0=Whh0, slot1=Wih1, slot2=Whh1
  __shared__ half8v fcw_c[16][4];      // fcW broadcast B-frags (same sigma)
  __shared__ float  bias_lds[4][16];   // e0,e1,d0,d1 (bih+bhh)
  __shared__ float  w0v_lds[2][16];    // Wih0 col (enc,dec)
  __shared__ float  c_lds[2][NB][4];   // fp32 cell state
  __shared__ float  h_tmp[2][NB][4];   // fp32 h' staging
  __shared__ float  fcb_s;

  const int wg   = blockIdx.x;
  const int tid  = threadIdx.x;
  const int lane = tid & 63;
  const int wv   = tid >> 6;
  const int Mb   = wv * 16;
  const int lo4  = lane >> 4;
  const int nn   = lane & 15;
  const int q    = nn >> 2, r = nn & 3;
  const int wksl = (wg >> 3) * 4 + (wg & 3);   // writer ks4 slot
  const int whi  = (wg >> 2) & 1;              // writer 8B half (e<4 / e>=4)

  unsigned epoch = 0;

  // ---- grid barrier: 16 relaxed monotone counters, s_sleep poll backoff ----
  auto gbar = [&]() {
    epoch++;
    __syncthreads();                   // compiler drains vmcnt(0) before s_barrier
    if (tid == 0)
      __hip_atomic_fetch_add(p.cnt + (wg & 15) * 32, 1u,
                             __ATOMIC_RELAXED, __HIP_MEMORY_SCOPE_AGENT);
    if (tid < 16) {
      const unsigned tgt = 8u * epoch;
      while (__hip_atomic_load(p.cnt + tid * 32,
                               __ATOMIC_RELAXED, __HIP_MEMORY_SCOPE_AGENT) < tgt)
        __builtin_amdgcn_s_sleep(2);
    }
    __builtin_amdgcn_fence(__ATOMIC_ACQUIRE, "workgroup");
    __syncthreads();
  };

  // -------- weight gather: global fp32 -> LDS fp16 B-frags (sigma) --------
  auto loadW = [&](int slot, const float *__restrict__ W) {
    for (int idx = tid; idx < 16 * 64; idx += NTHR) {
      const int ks = idx >> 6, l = idx & 63;
      const int g = 4 * wg + (l & 3) + 512 * ((l >> 2) & 3);
      const float *base = W + (size_t)g * NH + 32 * ks + 4 * (l >> 4);
      f32x4 wa, wb;
      __builtin_memcpy(&wa, base, 16);
      __builtin_memcpy(&wb, base + 16, 16);
      half8v h;
      h[0] = (_Float16)wa[0]; h[1] = (_Float16)wa[1];
      h[2] = (_Float16)wa[2]; h[3] = (_Float16)wa[3];
      h[4] = (_Float16)wb[0]; h[5] = (_Float16)wb[1];
      h[6] = (_Float16)wb[2]; h[7] = (_Float16)wb[3];
      wlds[slot][ks][l] = h;
    }
  };

  // -------- A-fragment load: 32 x 8B agent-atomic, staged then packed --------
  auto ldA = [&](const unsigned short* Hb, half8v* A) {
    const uint64_t* bp = (const uint64_t*)Hb + (size_t)(Mb + nn) * 2 + lo4 * 128;
    uint64_t u0[16], u1[16];
#pragma unroll
    for (int ks = 0; ks < 16; ++ks) {
      u0[ks] = ldg64(bp + ks * 512);
      u1[ks] = ldg64(bp + ks * 512 + 1);
    }
#pragma unroll
    for (int ks = 0; ks < 16; ++ks) {
      union { uint64_t u[2]; half8v h; } T;
      T.u[0] = u0[ks]; T.u[1] = u1[ks];
      A[ks] = T.h;
    }
  };

  // -------- gates -> (c,h'); h' fp32 into h_tmp[sel] --------
  auto cell = [&](const f32x4 &acc, const float* bias16, const float* w016,
                  const float* xv4, int sel, float* cl) {
    float v[4];
#pragma unroll
    for (int j = 0; j < 4; ++j) {
      const float g = acc[j] + bias16[nn] + xv4[j] * w016[nn];
      v[j] = (q == 2) ? tanhf_(g) : sigf(g);
    }
    float s4[4], s8[4], s12[4];
#pragma unroll
    for (int j = 0; j < 4; ++j) {
      s4[j]  = __shfl_xor(v[j], 4, 64);
      s8[j]  = __shfl_xor(v[j], 8, 64);
      s12[j] = __shfl_xor(v[j], 12, 64);
    }
    if (q == 0) {
#pragma unroll
      for (int j = 0; j < 4; ++j) {
        const int b = Mb + 4 * lo4 + j;
        const float co = cl[b * 4 + r];
        const float cn = s4[j] * co + v[j] * s8[j];
        cl[b * 4 + r] = cn;
        h_tmp[sel][b][r] = s12[j] * tanhf_(cn);
      }
    }
  };

  auto packrow = [&](int sel, int b) -> uint64_t {
    union { uint64_t u; _Float16 h[4]; } cv;
#pragma unroll
    for (int k = 0; k < 4; ++k) cv.h[k] = (_Float16)h_tmp[sel][b][k];
    return cv.u;
  };
  auto publish = [&](unsigned short* Hpar, int sel, int b) {
    stg64((uint64_t*)Hpar + ((size_t)wksl * 64 + b) * 2 + whi, packrow(sel, b));
  };

  // ================= init =================
  loadW(0, p.eWhh0); loadW(1, p.eWih1); loadW(2, p.eWhh1);
  if (tid < 16) {
    const int g = 4 * wg + (tid & 3) + 512 * (tid >> 2);
    bias_lds[0][tid] = p.ebih0[g] + p.ebhh0[g];
    bias_lds[1][tid] = p.ebih1[g] + p.ebhh1[g];
    bias_lds[2][tid] = p.dbih0[g] + p.dbhh0[g];
    bias_lds[3][tid] = p.dbih1[g] + p.dbhh1[g];
    w0v_lds[0][tid] = p.eWih0[g];
    w0v_lds[1][tid] = p.dWih0[g];
  }
  if (tid < 64) {                       // fcW broadcast B-frag (sigma)
    const int ks = tid >> 2, l4 = tid & 3;
    half8v h;
#pragma unroll
    for (int j = 0; j < 4; ++j) {
      h[j]     = (_Float16)p.fcW[32 * ks + 4 * l4 + j];
      h[4 + j] = (_Float16)p.fcW[32 * ks + 4 * l4 + 16 + j];
    }
    fcw_c[ks][l4] = h;
  }
  if (tid == 0) fcb_s = p.fcb[0];
  for (int i = tid; i < 2 * NB * 4; i += NTHR) (&c_lds[0][0][0])[i] = 0.f;
  if (tid < 64) {                       // h0(-1)=0 in H0[1]; h1(-1)=0 in H1[0]
    stg64((uint64_t*)(p.H0 + 32768) + ((size_t)wksl * 64 + tid) * 2 + whi, 0ull);
    stg64((uint64_t*)p.H1 + ((size_t)wksl * 64 + tid) * 2 + whi, 0ull);
  }
  float xv[4];
#pragma unroll
  for (int j = 0; j < 4; ++j) xv[j] = p.x[(size_t)(Mb + 4 * lo4 + j) * SEQ];
  const float zv4[4] = {0.f, 0.f, 0.f, 0.f};
  gbar();

  // ================= encoder: L0(t) || L1(t-1), 1 barrier/phase =================
  for (int t = 0; t <= SEQ; ++t) {
    const int ri = (t + 1) & 1, wi = t & 1;
    const bool d0 = (t < SEQ), d1 = (t > 0);
    half8v A0[16], A1[16];
    ldA(p.H0 + ri * 32768, A0);                  // h0(t-1)
    if (d1) ldA(p.H1 + ri * 32768, A1);          // h1(t-2)  (issued before MFMA)
    f32x4 aL0 = {0.f, 0.f, 0.f, 0.f}, aL1 = {0.f, 0.f, 0.f, 0.f};
#pragma unroll
    for (int ks = 0; ks < 16; ++ks) {
      if (d0) aL0 = __builtin_amdgcn_mfma_f32_16x16x32_f16(A0[ks], wlds[0][ks][lane], aL0, 0, 0, 0);
      if (d1) aL1 = __builtin_amdgcn_mfma_f32_16x16x32_f16(A0[ks], wlds[1][ks][lane], aL1, 0, 0, 0);
    }
    if (d1) {
#pragma unroll
      for (int ks = 0; ks < 16; ++ks)
        aL1 = __builtin_amdgcn_mfma_f32_16x16x32_f16(A1[ks], wlds[2][ks][lane], aL1, 0, 0, 0);
    }
    if (d0) cell(aL0, bias_lds[0], w0v_lds[0], xv, 0, &c_lds[0][0][0]);
    if (d1) cell(aL1, bias_lds[1], w0v_lds[0], zv4, 1, &c_lds[1][0][0]);
    if (t + 1 < SEQ) {
#pragma unroll
      for (int j = 0; j < 4; ++j) xv[j] = p.x[(size_t)(Mb + 4 * lo4 + j) * SEQ + (t + 1)];
    }
    __syncthreads();
    if (tid < 64) {
      if (d0) publish(p.H0 + wi * 32768, 0, tid);
      if (d1) publish(p.H1 + wi * 32768, 1, tid);
    }
    gbar();
  }
  // encoder leaves: h0_enc in H0[1], h1_enc in H1[0]

  // ================= enc -> dec transition =================
  loadW(0, p.dWhh0); loadW(1, p.dWih1); loadW(2, p.dWhh1);
  __syncthreads();
  f32x4 accPre0 = {0.f, 0.f, 0.f, 0.f};
  {
    half8v A[16];
    ldA(p.H0 + 32768, A);                        // h0_enc
#pragma unroll
    for (int ks = 0; ks < 16; ++ks)
      accPre0 = __builtin_amdgcn_mfma_f32_16x16x32_f16(A[ks], wlds[0][ks][lane], accPre0, 0, 0, 0);
  }

  // ============ decoder: A(t)=fc+Whh1+cell0, B(t)=Wih1+Whh0+cell1 ============
  f32x4 acc1c = {0.f, 0.f, 0.f, 0.f};
  for (int t = 0; t < SEQ; ++t) {
    { // ---- A(t): reads h1(t-1) in H1[t&1] ----
      half8v A[16];
      ldA(p.H1 + (t & 1) * 32768, A);
      f32x4 aP1 = {0.f, 0.f, 0.f, 0.f}, afc = {0.f, 0.f, 0.f, 0.f};
#pragma unroll
      for (int ks = 0; ks < 16; ++ks) {
        aP1 = __builtin_amdgcn_mfma_f32_16x16x32_f16(A[ks], wlds[2][ks][lane], aP1, 0, 0, 0);
        afc = __builtin_amdgcn_mfma_f32_16x16x32_f16(A[ks], fcw_c[ks][lo4],    afc, 0, 0, 0);
      }
      acc1c = aP1;
      float yv4[4];
#pragma unroll
      for (int j = 0; j < 4; ++j) yv4[j] = (t == 0) ? 0.f : (afc[j] + fcb_s);
      if (t > 0 && wg == 0 && nn == 0) {
#pragma unroll
        for (int j = 0; j < 4; ++j)
          p.out[(size_t)(Mb + 4 * lo4 + j) * SEQ + (t - 1)] = yv4[j];
      }
      cell(accPre0, bias_lds[2], w0v_lds[1], yv4, 0, &c_lds[0][0][0]);
      __syncthreads();
      if (tid < 64) publish(p.H0 + (t & 1) * 32768, 0, tid);
      gbar();
    }
    { // ---- B(t): reads h0(t) in H0[t&1] ----
      half8v A[16];
      ldA(p.H0 + (t & 1) * 32768, A);
      f32x4 a0n = {0.f, 0.f, 0.f, 0.f};
#pragma unroll
      for (int ks = 0; ks < 16; ++ks) {
        acc1c = __builtin_amdgcn_mfma_f32_16x16x32_f16(A[ks], wlds[1][ks][lane], acc1c, 0, 0, 0);
        a0n   = __builtin_amdgcn_mfma_f32_16x16x32_f16(A[ks], wlds[0][ks][lane], a0n,   0, 0, 0);
      }
      cell(acc1c, bias_lds[3], w0v_lds[1], zv4, 1, &c_lds[1][0][0]);
      accPre0 = a0n;
      __syncthreads();
      if (tid < 64) publish(p.H1 + ((t + 1) & 1) * 32768, 1, tid);
      gbar();
    }
  }

  // ================= epilogue: y(2047) = fc(h1(2047)) in H1[0] =================
  if (wg == 0) {
    half8v A[16];
    ldA(p.H1, A);
    f32x4 afc = {0.f, 0.f, 0.f, 0.f};
#pragma unroll
    for (int ks = 0; ks < 16; ++ks)
      afc = __builtin_amdgcn_mfma_f32_16x16x32_f16(A[ks], fcw_c[ks][lo4], afc, 0, 0, 0);
    if (nn == 0) {
#pragma unroll
      for (int j = 0; j < 4; ++j)
        p.out[(size_t)(Mb + 4 * lo4 + j) * SEQ + (SEQ - 1)] = afc[j] + fcb_s;
    }
  }
}

extern "C" void kernel_launch(void* const* d_in, const int* in_sizes, int n_in,
                              void* d_out, int out_size, void* d_ws, size_t ws_size,
                              hipStream_t stream) {
  (void)in_sizes; (void)n_in; (void)out_size; (void)ws_size;
  P p;
  p.x     = (const float*)d_in[0];
  p.eWih0 = (const float*)d_in[1];  p.eWhh0 = (const float*)d_in[2];
  p.ebih0 = (const float*)d_in[3];  p.ebhh0 = (const float*)d_in[4];
  p.eWih1 = (const float*)d_in[5];  p.eWhh1 = (const float*)d_in[6];
  p.ebih1 = (const float*)d_in[7];  p.ebhh1 = (const float*)d_in[8];
  p.dWih0 = (const float*)d_in[9];  p.dWhh0 = (const float*)d_in[10];
  p.dbih0 = (const float*)d_in[11]; p.dbhh0 = (const float*)d_in[12];
  p.dWih1 = (const float*)d_in[13]; p.dWhh1 = (const float*)d_in[14];
  p.dbih1 = (const float*)d_in[15]; p.dbhh1 = (const float*)d_in[16];
  p.fcW   = (const float*)d_in[17]; p.fcb   = (const float*)d_in[18];
  p.out   = (float*)d_out;

  p.H0  = (unsigned short*)d_ws;                 // 128 KB (2 parities x 64 KB)
  p.H1  = (unsigned short*)d_ws + 2 * 32768;     // 128 KB
  p.cnt = (unsigned*)((char*)d_ws + 262144);     // 16 x 128B counters

  // Zero the barrier counters every call (graph-capturable, replay-safe).
  hipMemsetAsync((char*)d_ws + 262144, 0, 2048, stream);

  lstm_persist<<<dim3(NWG), dim3(NTHR), 0, stream>>>(p);
}